// Round 16
// baseline (245.966 us; speedup 1.0000x reference)
//
#include <hip/hip_runtime.h>
#include <stdint.h>

// PointNet SA via MFMA, v11: NO LDS gather — stage-g B-fragments load DIRECTLY
// from the pre-transposed featT (L3-resident, [n][c] row-major is exactly the
// B-frag layout; 4 q-lanes of a point = one 64B line). xyz-diff patched into
// cols 0-2 in-register. Kills the gather phase (barrier + 2048 LDS writes +
// serialized L3 drain); each wave starts MFMA immediately (natural de-sync).
// LDS only holds X0/X1/X2 (32KB, X2 aliases X0+X1). bf16 packing via
// v_cvt_pk_bf16_f32 (RNE, 3x fewer VALU than manual).

namespace {
constexpr int kB = 4, kN = 16384, kC = 103, kP = 2048, kS = 32;

using short8 = __attribute__((ext_vector_type(8))) short;
using short4 = __attribute__((ext_vector_type(4))) short;
using f32x4  = __attribute__((ext_vector_type(4))) float;

constexpr int WG_HI = 0,     WG_LO = 8192;     // 64 x 128
constexpr int W1_HI = 16384, W1_LO = 20480;    // 64 x 64
constexpr int W2_HI = 24576, W2_LO = 32768;    // 128 x 64
constexpr int W3_HI = 40960, W3_LO = 73728;    // 256 x 128
constexpr size_t FT_OFF    = 262144;
constexpr size_t FT_SHORTS = (size_t)kB * kN * 128;
constexpr size_t WS_NEED   = FT_OFF + 2 * FT_SHORTS * 2;

__device__ __forceinline__ unsigned short f2bf(float x) {
    unsigned u = __float_as_uint(x);
    u += 0x7fffu + ((u >> 16) & 1u);           // RNE
    return (unsigned short)(u >> 16);
}
__device__ __forceinline__ float bf2f(unsigned short h) {
    return __uint_as_float((unsigned)h << 16);
}
// packed RNE: bits[15:0]=bf16(a), bits[31:16]=bf16(b)
__device__ __forceinline__ unsigned cvtpk(float a, float b) {
    unsigned r;
    asm("v_cvt_pk_bf16_f32 %0, %1, %2" : "=v"(r) : "v"(a), "v"(b));
    return r;
}
// pack 4 f32 -> hi-plane uint2 + lo-plane uint2 (hi/lo bf16 split, RNE)
__device__ __forceinline__ void pack4(const float v[4], uint2& H, uint2& L) {
    H.x = cvtpk(v[0], v[1]);
    H.y = cvtpk(v[2], v[3]);
    const float r0 = v[0] - __uint_as_float(H.x << 16);
    const float r1 = v[1] - __uint_as_float(H.x & 0xffff0000u);
    const float r2 = v[2] - __uint_as_float(H.y << 16);
    const float r3 = v[3] - __uint_as_float(H.y & 0xffff0000u);
    L.x = cvtpk(r0, r1);
    L.y = cvtpk(r2, r3);
}

__global__ void copy_newxyz(const float* __restrict__ src, float* __restrict__ dst, int n) {
    int i = blockIdx.x * blockDim.x + threadIdx.x;
    if (i < n) dst[i] = src[i];
}

__global__ void prep_weights(const float* __restrict__ Wg, const float* __restrict__ W1,
                             const float* __restrict__ W2, const float* __restrict__ W3,
                             short* __restrict__ ws) {
    int i = blockIdx.x * blockDim.x + threadIdx.x;
    if (i >= 53248) return;
    float w; int hi, lo, j;
    if (i < 8192)       { j = i;         int o = j >> 7, c = j & 127; w = (c < 106) ? Wg[o * 106 + c] : 0.f; hi = WG_HI; lo = WG_LO; }
    else if (i < 12288) { j = i - 8192;  int o = j >> 6, c = j & 63;  w = W1[o * 64 + c];  hi = W1_HI; lo = W1_LO; }
    else if (i < 20480) { j = i - 12288; int o = j >> 6, c = j & 63;  w = W2[o * 64 + c];  hi = W2_HI; lo = W2_LO; }
    else                { j = i - 20480; int o = j >> 7, c = j & 127; w = W3[o * 128 + c]; hi = W3_HI; lo = W3_LO; }
    unsigned short h = f2bf(w);
    ws[hi + j] = (short)h;
    ws[lo + j] = (short)f2bf(w - bf2f(h));
}

__global__ __launch_bounds__(512) void prep_feat(const float* __restrict__ f,
                                                 short* __restrict__ ftH, short* __restrict__ ftL) {
    __shared__ float tile[kC][65];
    const int bb = blockIdx.x >> 8;
    const int n0 = (blockIdx.x & 255) * 64;
    const int tid = threadIdx.x;
    for (int c = tid >> 6; c < kC; c += 8)
        tile[c][tid & 63] = f[((size_t)bb * kC + c) * kN + n0 + (tid & 63)];
    __syncthreads();
    const int np = tid >> 3, gc = tid & 7;
    short* rH = ftH + ((size_t)bb * kN + n0 + np) * 128;
    short* rL = ftL + ((size_t)bb * kN + n0 + np) * 128;
    #pragma unroll
    for (int kk = 0; kk < 2; ++kk) {
        const int chunk = gc + 8 * kk;
        union { uint4 u; short s[8]; } H, L;
        #pragma unroll
        for (int e = 0; e < 8; ++e) {
            const int col = chunk * 8 + e;
            float v = (col >= 3 && col < 106) ? tile[col - 3][np] : 0.f;
            unsigned short hh = f2bf(v);
            H.s[e] = (short)hh;
            L.s[e] = (short)f2bf(v - bf2f(hh));
        }
        *(uint4*)(rH + chunk * 8) = H.u;
        *(uint4*)(rL + chunk * 8) = L.u;
    }
}

// A: m=lane&15 (W row), k=8*(lane>>4)+j; B: n=lane&15 (point), same k; D: n=lane&15, m=4*(lane>>4)+r
template<int NOT, int NPT, int KT, int LDC, int LDW>
__device__ __forceinline__ void gemm_lds(
    const short* __restrict__ xh, const short* __restrict__ xl,
    const short* __restrict__ wh, const short* __restrict__ wl,
    const float* __restrict__ bias,
    int ot0, int pt0t, int lane, f32x4 (&acc)[NOT][NPT])
{
    const int q = lane >> 4, n16 = lane & 15;
    #pragma unroll
    for (int i = 0; i < NOT; ++i) {
        const f32x4 binit = *(const f32x4*)(bias + (ot0 + i) * 16 + 4 * q);
        #pragma unroll
        for (int j = 0; j < NPT; ++j) acc[i][j] = binit;
    }
    #pragma unroll
    for (int kt = 0; kt < KT; ++kt) {
        const int k0 = kt * 32 + q * 8;
        short8 bh[NPT], bl[NPT];
        #pragma unroll
        for (int j = 0; j < NPT; ++j) {
            const int p = (pt0t + j) * 16 + n16;
            const int e = p * LDC + (k0 ^ ((p & 7) << 3));
            bh[j] = *(const short8*)(xh + e);
            bl[j] = *(const short8*)(xl + e);
        }
        #pragma unroll
        for (int i = 0; i < NOT; ++i) {
            const size_t we = (size_t)((ot0 + i) * 16 + n16) * LDW + k0;
            const short8 ah = *(const short8*)(wh + we);
            const short8 al = *(const short8*)(wl + we);
            #pragma unroll
            for (int j = 0; j < NPT; ++j) {
                acc[i][j] = __builtin_amdgcn_mfma_f32_16x16x32_bf16(ah, bh[j], acc[i][j], 0, 0, 0);
                acc[i][j] = __builtin_amdgcn_mfma_f32_16x16x32_bf16(ah, bl[j], acc[i][j], 0, 0, 0);
                acc[i][j] = __builtin_amdgcn_mfma_f32_16x16x32_bf16(al, bh[j], acc[i][j], 0, 0, 0);
            }
        }
    }
}

template<int NOT, int NPT, int LDCO>
__device__ __forceinline__ void store_relu(
    f32x4 (&acc)[NOT][NPT], short* __restrict__ oh, short* __restrict__ ol,
    int ot0, int pt0t, int lane)
{
    const int q = lane >> 4, n16 = lane & 15;
    #pragma unroll
    for (int i = 0; i < NOT; ++i) {
        const int ob = (ot0 + i) * 16 + 4 * q;
        #pragma unroll
        for (int j = 0; j < NPT; ++j) {
            const int p = (pt0t + j) * 16 + n16;
            const int cs = ob ^ ((p & 7) << 3);
            float v[4];
            #pragma unroll
            for (int r = 0; r < 4; ++r) v[r] = fmaxf(acc[i][j][r], 0.f);
            uint2 H, L;
            pack4(v, H, L);
            *(uint2*)(oh + p * LDCO + cs) = H;
            *(uint2*)(ol + p * LDCO + cs) = L;
        }
    }
}

// ---------------- direct (dense) kernel: no NF LDS ----------------
__global__ __launch_bounds__(512, 3) void pointnet_sa_direct(
    const float* __restrict__ xyz, const float* __restrict__ new_xyz,
    const int* __restrict__ idx,
    const short* __restrict__ ws, const short* __restrict__ ftH, const short* __restrict__ ftL,
    const float* __restrict__ bg, const float* __restrict__ b1,
    const float* __restrict__ b2, const float* __restrict__ b3,
    float* __restrict__ out_pooled)  // (B, 256, P)
{
    __shared__ alignas(16) short smem[16384];       // 32 KB
    short* X0h = smem;                               // [64][64]
    short* X0l = smem + 4096;
    short* X1h = smem + 8192;                        // [64][64]
    short* X1l = smem + 12288;
    short* X2h = smem;                               // [64][128] alias X0
    short* X2l = smem + 8192;                        // [64][128] alias X1

    const int tid = threadIdx.x, lane = tid & 63, wave = tid >> 6;
    const int q = lane >> 4, n16 = lane & 15;
    const int pt0 = blockIdx.x * 64;
    const int b = pt0 >> 16;                         // P*S = 65536 points per batch
    const size_t fbase = (size_t)b * kN;

    // ---- stage g: B-frags direct from featT; cols 0-2 patched with xyz-diff ----
    {
        const int ot = wave & 3, ptp = 2 * (wave >> 2);
        const int ptA = pt0 + ptp * 16 + n16;
        const int nA = idx[ptA];
        const int nB = idx[ptA + 16];
        const short* fhA = ftH + (fbase + nA) * 128;
        const short* flA = ftL + (fbase + nA) * 128;
        const short* fhB = ftH + (fbase + nB) * 128;
        const short* flB = ftL + (fbase + nB) * 128;

        // xyz-diff patch values (cols 0-2), q==0 lanes only
        float xb0[3], xb1[3];
        unsigned short pxh0[3], pxl0[3], pxh1[3], pxl1[3];
        if (q == 0) {
            #pragma unroll
            for (int j = 0; j < 2; ++j) {
                const int ptf = ptA + j * 16;
                const int nj = j ? nB : nA;
                const int pp = (ptf >> 5) & (kP - 1);
                const float* xp = xyz + (fbase + nj) * 3;
                const float* np = new_xyz + ((size_t)b * kP + pp) * 3;
                #pragma unroll
                for (int c = 0; c < 3; ++c) {
                    const float xd = xp[c] - np[c];
                    const unsigned short h = f2bf(xd);
                    if (j) { xb1[c] = xd; pxh1[c] = h; pxl1[c] = f2bf(xd - bf2f(h)); }
                    else   { xb0[c] = xd; pxh0[c] = h; pxl0[c] = f2bf(xd - bf2f(h)); }
                }
            }
        }

        f32x4 acc0, acc1;
        {
            const f32x4 binit = *(const f32x4*)(bg + ot * 16 + 4 * q);
            acc0 = binit; acc1 = binit;
        }
        #pragma unroll
        for (int kt = 0; kt < 4; ++kt) {
            const int ko = kt * 32 + q * 8;
            short8 bhA = *(const short8*)(fhA + ko);
            short8 blA = *(const short8*)(flA + ko);
            short8 bhB = *(const short8*)(fhB + ko);
            short8 blB = *(const short8*)(flB + ko);
            if (kt == 0 && q == 0) {
                bhA[0] = (short)pxh0[0]; bhA[1] = (short)pxh0[1]; bhA[2] = (short)pxh0[2];
                blA[0] = (short)pxl0[0]; blA[1] = (short)pxl0[1]; blA[2] = (short)pxl0[2];
                bhB[0] = (short)pxh1[0]; bhB[1] = (short)pxh1[1]; bhB[2] = (short)pxh1[2];
                blB[0] = (short)pxl1[0]; blB[1] = (short)pxl1[1]; blB[2] = (short)pxl1[2];
            }
            const size_t we = (size_t)(ot * 16 + n16) * 128 + ko;
            const short8 ah = *(const short8*)(ws + WG_HI + we);
            const short8 al = *(const short8*)(ws + WG_LO + we);
            acc0 = __builtin_amdgcn_mfma_f32_16x16x32_bf16(ah, bhA, acc0, 0, 0, 0);
            acc0 = __builtin_amdgcn_mfma_f32_16x16x32_bf16(ah, blA, acc0, 0, 0, 0);
            acc0 = __builtin_amdgcn_mfma_f32_16x16x32_bf16(al, bhA, acc0, 0, 0, 0);
            acc1 = __builtin_amdgcn_mfma_f32_16x16x32_bf16(ah, bhB, acc1, 0, 0, 0);
            acc1 = __builtin_amdgcn_mfma_f32_16x16x32_bf16(ah, blB, acc1, 0, 0, 0);
            acc1 = __builtin_amdgcn_mfma_f32_16x16x32_bf16(al, bhB, acc1, 0, 0, 0);
        }

        // gate: x0 = base*(1+w); base direct from featT (cols<3 patched)
        const int ob = ot * 16 + 4 * q;
        #pragma unroll
        for (int j = 0; j < 2; ++j) {
            const int pl = (ptp + j) * 16 + n16;
            const short* fh = j ? fhB : fhA;
            const short* fl = j ? flB : flA;
            const uint2 bh4 = *(const uint2*)(fh + ob);
            const uint2 bl4 = *(const uint2*)(fl + ob);
            float base[4];
            base[0] = __uint_as_float(bh4.x << 16)          + __uint_as_float(bl4.x << 16);
            base[1] = __uint_as_float(bh4.x & 0xffff0000u)  + __uint_as_float(bl4.x & 0xffff0000u);
            base[2] = __uint_as_float(bh4.y << 16)          + __uint_as_float(bl4.y << 16);
            base[3] = __uint_as_float(bh4.y & 0xffff0000u)  + __uint_as_float(bl4.y & 0xffff0000u);
            if (ot == 0 && q == 0) {
                base[0] = j ? xb1[0] : xb0[0];
                base[1] = j ? xb1[1] : xb0[1];
                base[2] = j ? xb1[2] : xb0[2];
            }
            const f32x4 A = j ? acc1 : acc0;
            float v[4];
            #pragma unroll
            for (int r = 0; r < 4; ++r) v[r] = fmaf(base[r], A[r], base[r]);
            uint2 H, L;
            pack4(v, H, L);
            const int cs = ob ^ ((pl & 7) << 3);
            *(uint2*)(X0h + pl * 64 + cs) = H;
            *(uint2*)(X0l + pl * 64 + cs) = L;
        }
    }
    __syncthreads();                                 // B1: x0 visible

    // ---- stage 1: x1 = relu(W1*x0 + b1) ----
    {
        f32x4 a[1][2];
        gemm_lds<1, 2, 2, 64, 64>(X0h, X0l, ws + W1_HI, ws + W1_LO, b1,
                                  wave & 3, 2 * (wave >> 2), lane, a);
        store_relu<1, 2, 64>(a, X1h, X1l, wave & 3, 2 * (wave >> 2), lane);
    }
    __syncthreads();                                 // B2: x1 visible (x0 dead)

    // ---- stage 2: x2 = relu(W2*x1 + b2) ----
    f32x4 a2[2][2];
    gemm_lds<2, 2, 2, 64, 64>(X1h, X1l, ws + W2_HI, ws + W2_LO, b2,
                              2 * (wave & 3), 2 * (wave >> 2), lane, a2);
    __syncthreads();                                 // B3: all x1 reads done
    store_relu<2, 2, 128>(a2, X2h, X2l, 2 * (wave & 3), 2 * (wave >> 2), lane);
    __syncthreads();                                 // B4: x2 visible

    // ---- stage 3 + max-pool over s (32 pts = 2 p-tiles) ----
    {
        f32x4 a[2][4];
        gemm_lds<2, 4, 4, 128, 128>(X2h, X2l, ws + W3_HI, ws + W3_LO, b3,
                                    2 * wave, 0, lane, a);
        #pragma unroll
        for (int i = 0; i < 2; ++i) {
            #pragma unroll
            for (int sg = 0; sg < 2; ++sg) {
                #pragma unroll
                for (int r = 0; r < 4; ++r) {
                    float v = fmaxf(a[i][2 * sg][r], a[i][2 * sg + 1][r]);
                    v = fmaxf(v, __shfl_xor(v, 1, 16));
                    v = fmaxf(v, __shfl_xor(v, 2, 16));
                    v = fmaxf(v, __shfl_xor(v, 4, 16));
                    v = fmaxf(v, __shfl_xor(v, 8, 16));
                    v = fmaxf(v, 0.f);
                    if (n16 == 0) {
                        const int o = (2 * wave + i) * 16 + 4 * q + r;
                        const int g = (pt0 >> 5) + sg;                 // flat b*P + p
                        out_pooled[((size_t)(g >> 11) * 256 + o) * kP + (g & (kP - 1))] = v;
                    }
                }
            }
        }
    }
}

// ---------------- scalar fallback (v10, 48KB LDS) ----------------
__global__ __launch_bounds__(512, 2) void pointnet_sa_scalar(
    const float* __restrict__ xyz, const float* __restrict__ features,
    const float* __restrict__ new_xyz, const int* __restrict__ idx,
    const short* __restrict__ ws,
    const float* __restrict__ bg, const float* __restrict__ b1,
    const float* __restrict__ b2, const float* __restrict__ b3,
    float* __restrict__ out_pooled)
{
    __shared__ alignas(16) short smem[24576];
    short* NFh = smem;
    short* NFl = smem + 8192;
    short* X0h = smem + 16384;
    short* X0l = smem + 20480;

    const int tid = threadIdx.x, lane = tid & 63, wave = tid >> 6;
    const int q = lane >> 4, n16 = lane & 15;
    const int pt0 = blockIdx.x * 64;
    const int b = pt0 >> 16;

    {
        const int p = tid & 63;
        const int cg = tid >> 6;
        const int pt = pt0 + p;
        const int n = idx[pt];
        const int pp = (pt >> 5) & (kP - 1);
        const float* fbp = features + (size_t)b * kC * kN + n;
        const float* xp = xyz + ((size_t)b * kN + n) * 3;
        const float* np = new_xyz + ((size_t)b * kP + pp) * 3;
        for (int c = cg; c < 128; c += 8) {
            float v;
            if (c < 3)        v = xp[c] - np[c];
            else if (c < 106) v = fbp[(size_t)(c - 3) * kN];
            else              v = 0.f;
            const unsigned short h = f2bf(v);
            const int cs = c ^ ((p & 7) << 3);
            NFh[p * 128 + cs] = (short)h;
            NFl[p * 128 + cs] = (short)f2bf(v - bf2f(h));
        }
    }
    __syncthreads();
    {
        f32x4 a[1][2];
        gemm_lds<1, 2, 4, 128, 128>(NFh, NFl, ws + WG_HI, ws + WG_LO, bg,
                                    wave & 3, 2 * (wave >> 2), lane, a);
        // gate using NF base
        const int ot0 = wave & 3, ptp = 2 * (wave >> 2);
        const int ob = ot0 * 16 + 4 * q;
        #pragma unroll
        for (int j = 0; j < 2; ++j) {
            const int p = (ptp + j) * 16 + n16;
            const int cs = ob ^ ((p & 7) << 3);
            const short4 h4 = *(const short4*)(NFh + p * 128 + cs);
            const short4 l4 = *(const short4*)(NFl + p * 128 + cs);
            float v[4];
            #pragma unroll
            for (int r = 0; r < 4; ++r) {
                const float base = bf2f((unsigned short)h4[r]) + bf2f((unsigned short)l4[r]);
                v[r] = fmaf(base, a[0][j][r], base);
            }
            uint2 H, L;
            pack4(v, H, L);
            *(uint2*)(X0h + p * 64 + cs) = H;
            *(uint2*)(X0l + p * 64 + cs) = L;
        }
    }
    __syncthreads();
    {
        f32x4 a[1][2];
        gemm_lds<1, 2, 2, 64, 64>(X0h, X0l, ws + W1_HI, ws + W1_LO, b1,
                                  wave & 3, 2 * (wave >> 2), lane, a);
        store_relu<1, 2, 128>(a, NFh, NFl, wave & 3, 2 * (wave >> 2), lane);
    }
    __syncthreads();
    {
        f32x4 a[2][2];
        gemm_lds<2, 2, 2, 128, 64>(NFh, NFl, ws + W2_HI, ws + W2_LO, b2,
                                   2 * (wave & 3), 2 * (wave >> 2), lane, a);
        __syncthreads();
        if ((wave & 3) < 2)
            store_relu<2, 2, 64>(a, X0h, X0l, 2 * (wave & 3), 2 * (wave >> 2), lane);
        else
            store_relu<2, 2, 128>(a, NFh + 64, NFl + 64, (2 * (wave & 3)) & 3,
                                  2 * (wave >> 2), lane);
    }
    __syncthreads();
    {
        f32x4 a[2][4];
        gemm_lds<2, 4, 2, 64, 128>(X0h, X0l, ws + W3_HI, ws + W3_LO, b3,
                                   2 * wave, 0, lane, a);
        // second half of K from NF cols 64-127 (accumulate manually)
        {
            const int q2 = lane >> 4, nn = lane & 15;
            #pragma unroll
            for (int kt = 0; kt < 2; ++kt) {
                const int k0 = kt * 32 + q2 * 8;
                short8 bh[4], bl[4];
                #pragma unroll
                for (int j = 0; j < 4; ++j) {
                    const int p = j * 16 + nn;
                    const int e = p * 128 + (k0 ^ ((p & 7) << 3));
                    bh[j] = *(const short8*)(NFh + 64 + e);
                    bl[j] = *(const short8*)(NFl + 64 + e);
                }
                #pragma unroll
                for (int i = 0; i < 2; ++i) {
                    const size_t we = (size_t)((2 * wave + i) * 16 + nn) * 128 + 64 + k0;
                    const short8 ah = *(const short8*)(ws + W3_HI + we);
                    const short8 al = *(const short8*)(ws + W3_LO + we);
                    #pragma unroll
                    for (int j = 0; j < 4; ++j) {
                        a[i][j] = __builtin_amdgcn_mfma_f32_16x16x32_bf16(ah, bh[j], a[i][j], 0, 0, 0);
                        a[i][j] = __builtin_amdgcn_mfma_f32_16x16x32_bf16(ah, bl[j], a[i][j], 0, 0, 0);
                        a[i][j] = __builtin_amdgcn_mfma_f32_16x16x32_bf16(al, bh[j], a[i][j], 0, 0, 0);
                    }
                }
            }
        }
        #pragma unroll
        for (int i = 0; i < 2; ++i)
            #pragma unroll
            for (int sg = 0; sg < 2; ++sg)
                #pragma unroll
                for (int r = 0; r < 4; ++r) {
                    float v = fmaxf(a[i][2 * sg][r], a[i][2 * sg + 1][r]);
                    v = fmaxf(v, __shfl_xor(v, 1, 16));
                    v = fmaxf(v, __shfl_xor(v, 2, 16));
                    v = fmaxf(v, __shfl_xor(v, 4, 16));
                    v = fmaxf(v, __shfl_xor(v, 8, 16));
                    v = fmaxf(v, 0.f);
                    if (n16 == 0) {
                        const int o = (2 * wave + i) * 16 + 4 * q + r;
                        const int g = (pt0 >> 5) + sg;
                        out_pooled[((size_t)(g >> 11) * 256 + o) * kP + (g & (kP - 1))] = v;
                    }
                }
    }
}
}  // namespace

extern "C" void kernel_launch(void* const* d_in, const int* in_sizes, int n_in,
                              void* d_out, int out_size, void* d_ws, size_t ws_size,
                              hipStream_t stream) {
    const float* xyz      = (const float*)d_in[0];
    const float* features = (const float*)d_in[1];
    const float* new_xyz  = (const float*)d_in[2];
    const int*   idx      = (const int*)d_in[3];
    const float* Wg = (const float*)d_in[4];
    const float* bg = (const float*)d_in[5];
    const float* W1 = (const float*)d_in[6];
    const float* b1 = (const float*)d_in[7];
    const float* W2 = (const float*)d_in[8];
    const float* b2 = (const float*)d_in[9];
    const float* W3 = (const float*)d_in[10];
    const float* b3 = (const float*)d_in[11];
    float* out = (float*)d_out;
    short* ws  = (short*)d_ws;
    short* ftH = (short*)((char*)d_ws + FT_OFF);
    short* ftL = ftH + FT_SHORTS;

    const int nxyz = kB * kP * 3;
    copy_newxyz<<<(nxyz + 255) / 256, 256, 0, stream>>>(new_xyz, out, nxyz);
    prep_weights<<<(53248 + 255) / 256, 256, 0, stream>>>(Wg, W1, W2, W3, ws);

    float* pooled = out + nxyz;
    if (ws_size >= WS_NEED) {
        prep_feat<<<kB * (kN / 64), 512, 0, stream>>>(features, ftH, ftL);
        pointnet_sa_direct<<<(kB * kP * kS) / 64, 512, 0, stream>>>(
            xyz, new_xyz, idx, ws, ftH, ftL, bg, b1, b2, b3, pooled);
    } else {
        pointnet_sa_scalar<<<(kB * kP * kS) / 64, 512, 0, stream>>>(
            xyz, features, new_xyz, idx, ws, bg, b1, b2, b3, pooled);
    }
}

// Round 17
// 227.846 us; speedup vs baseline: 1.0795x; 1.0795x over previous
//
#include <hip/hip_runtime.h>
#include <stdint.h>

// PointNet SA via MFMA, v12 = v10 structure at HALF block size:
// 32 pts / 256 threads / 4 waves / 24KB LDS -> up to 6 blocks/CU (vs 2 for the
// 512-thread versions). 6 independent barrier-schedules per CU de-correlate the
// convoy (v10's diagnosed limiter). Per-wave fragment work identical to v10.
// Each block = one s-group; pool fully in-wave. + v_cvt_pk_bf16_f32 packing.

namespace {
constexpr int kB = 4, kN = 16384, kC = 103, kP = 2048, kS = 32;

using short8 = __attribute__((ext_vector_type(8))) short;
using short4 = __attribute__((ext_vector_type(4))) short;
using f32x4  = __attribute__((ext_vector_type(4))) float;

constexpr int WG_HI = 0,     WG_LO = 8192;     // 64 x 128
constexpr int W1_HI = 16384, W1_LO = 20480;    // 64 x 64
constexpr int W2_HI = 24576, W2_LO = 32768;    // 128 x 64
constexpr int W3_HI = 40960, W3_LO = 73728;    // 256 x 128
constexpr size_t FT_OFF    = 262144;
constexpr size_t FT_SHORTS = (size_t)kB * kN * 128;
constexpr size_t WS_NEED   = FT_OFF + 2 * FT_SHORTS * 2;

__device__ __forceinline__ unsigned short f2bf(float x) {
    unsigned u = __float_as_uint(x);
    u += 0x7fffu + ((u >> 16) & 1u);           // RNE
    return (unsigned short)(u >> 16);
}
__device__ __forceinline__ float bf2f(unsigned short h) {
    return __uint_as_float((unsigned)h << 16);
}
__device__ __forceinline__ unsigned cvtpk(float a, float b) {
    unsigned r;
    asm("v_cvt_pk_bf16_f32 %0, %1, %2" : "=v"(r) : "v"(a), "v"(b));
    return r;
}
// pack 4 f32 -> hi-plane uint2 + lo-plane uint2 (hi/lo bf16 split, RNE)
__device__ __forceinline__ void pack4(const float v[4], uint2& H, uint2& L) {
    H.x = cvtpk(v[0], v[1]);
    H.y = cvtpk(v[2], v[3]);
    const float r0 = v[0] - __uint_as_float(H.x << 16);
    const float r1 = v[1] - __uint_as_float(H.x & 0xffff0000u);
    const float r2 = v[2] - __uint_as_float(H.y << 16);
    const float r3 = v[3] - __uint_as_float(H.y & 0xffff0000u);
    L.x = cvtpk(r0, r1);
    L.y = cvtpk(r2, r3);
}

__global__ void copy_newxyz(const float* __restrict__ src, float* __restrict__ dst, int n) {
    int i = blockIdx.x * blockDim.x + threadIdx.x;
    if (i < n) dst[i] = src[i];
}

__global__ void prep_weights(const float* __restrict__ Wg, const float* __restrict__ W1,
                             const float* __restrict__ W2, const float* __restrict__ W3,
                             short* __restrict__ ws) {
    int i = blockIdx.x * blockDim.x + threadIdx.x;
    if (i >= 53248) return;
    float w; int hi, lo, j;
    if (i < 8192)       { j = i;         int o = j >> 7, c = j & 127; w = (c < 106) ? Wg[o * 106 + c] : 0.f; hi = WG_HI; lo = WG_LO; }
    else if (i < 12288) { j = i - 8192;  int o = j >> 6, c = j & 63;  w = W1[o * 64 + c];  hi = W1_HI; lo = W1_LO; }
    else if (i < 20480) { j = i - 12288; int o = j >> 6, c = j & 63;  w = W2[o * 64 + c];  hi = W2_HI; lo = W2_LO; }
    else                { j = i - 20480; int o = j >> 7, c = j & 127; w = W3[o * 128 + c]; hi = W3_HI; lo = W3_LO; }
    unsigned short h = f2bf(w);
    ws[hi + j] = (short)h;
    ws[lo + j] = (short)f2bf(w - bf2f(h));
}

__global__ __launch_bounds__(512) void prep_feat(const float* __restrict__ f,
                                                 short* __restrict__ ftH, short* __restrict__ ftL) {
    __shared__ float tile[kC][65];
    const int bb = blockIdx.x >> 8;
    const int n0 = (blockIdx.x & 255) * 64;
    const int tid = threadIdx.x;
    for (int c = tid >> 6; c < kC; c += 8)
        tile[c][tid & 63] = f[((size_t)bb * kC + c) * kN + n0 + (tid & 63)];
    __syncthreads();
    const int np = tid >> 3, gc = tid & 7;
    short* rH = ftH + ((size_t)bb * kN + n0 + np) * 128;
    short* rL = ftL + ((size_t)bb * kN + n0 + np) * 128;
    #pragma unroll
    for (int kk = 0; kk < 2; ++kk) {
        const int chunk = gc + 8 * kk;
        union { uint4 u; short s[8]; } H, L;
        #pragma unroll
        for (int e = 0; e < 8; ++e) {
            const int col = chunk * 8 + e;
            float v = (col >= 3 && col < 106) ? tile[col - 3][np] : 0.f;
            unsigned short hh = f2bf(v);
            H.s[e] = (short)hh;
            L.s[e] = (short)f2bf(v - bf2f(hh));
        }
        *(uint4*)(rH + chunk * 8) = H.u;
        *(uint4*)(rL + chunk * 8) = L.u;
    }
}

// A: m=lane&15 (W row), k=8*(lane>>4)+j; B: n=lane&15 (point), same k; D: n=lane&15, m=4*(lane>>4)+r
template<int NOT, int NPT, int KT, int LDC, int LDW, bool INIT>
__device__ __forceinline__ void gemm_core(
    const short* __restrict__ xh, const short* __restrict__ xl,
    const short* __restrict__ wh, const short* __restrict__ wl,
    const float* __restrict__ bias, int kwoff,
    int ot0, int pt0t, int lane, f32x4 (&acc)[NOT][NPT])
{
    const int q = lane >> 4, n16 = lane & 15;
    if constexpr (INIT) {
        #pragma unroll
        for (int i = 0; i < NOT; ++i) {
            const f32x4 binit = *(const f32x4*)(bias + (ot0 + i) * 16 + 4 * q);
            #pragma unroll
            for (int j = 0; j < NPT; ++j) acc[i][j] = binit;
        }
    }
    #pragma unroll
    for (int kt = 0; kt < KT; ++kt) {
        const int k0 = kt * 32 + q * 8;
        short8 bh[NPT], bl[NPT];
        #pragma unroll
        for (int j = 0; j < NPT; ++j) {
            const int p = (pt0t + j) * 16 + n16;
            const int e = p * LDC + (k0 ^ ((p & 7) << 3));
            bh[j] = *(const short8*)(xh + e);
            bl[j] = *(const short8*)(xl + e);
        }
        #pragma unroll
        for (int i = 0; i < NOT; ++i) {
            const size_t we = (size_t)((ot0 + i) * 16 + n16) * LDW + kwoff + k0;
            const short8 ah = *(const short8*)(wh + we);
            const short8 al = *(const short8*)(wl + we);
            #pragma unroll
            for (int j = 0; j < NPT; ++j) {
                acc[i][j] = __builtin_amdgcn_mfma_f32_16x16x32_bf16(ah, bh[j], acc[i][j], 0, 0, 0);
                acc[i][j] = __builtin_amdgcn_mfma_f32_16x16x32_bf16(ah, bl[j], acc[i][j], 0, 0, 0);
                acc[i][j] = __builtin_amdgcn_mfma_f32_16x16x32_bf16(al, bh[j], acc[i][j], 0, 0, 0);
            }
        }
    }
}

// GATE: v = base*(1+acc) with base from NF planes; else relu. cvt_pk packing.
template<int NOT, int NPT, bool GATE, int LDCO>
__device__ __forceinline__ void store_act(
    f32x4 (&acc)[NOT][NPT], short* __restrict__ oh, short* __restrict__ ol,
    const short* __restrict__ nfh, const short* __restrict__ nfl,
    int ot0, int pt0t, int lane)
{
    const int q = lane >> 4, n16 = lane & 15;
    #pragma unroll
    for (int i = 0; i < NOT; ++i) {
        const int ob = (ot0 + i) * 16 + 4 * q;
        #pragma unroll
        for (int j = 0; j < NPT; ++j) {
            const int p = (pt0t + j) * 16 + n16;
            const int cs = ob ^ ((p & 7) << 3);
            float v[4];
            if (GATE) {
                const short4 h4 = *(const short4*)(nfh + p * 128 + cs);
                const short4 l4 = *(const short4*)(nfl + p * 128 + cs);
                #pragma unroll
                for (int r = 0; r < 4; ++r) {
                    const float base = bf2f((unsigned short)h4[r]) + bf2f((unsigned short)l4[r]);
                    v[r] = fmaf(base, acc[i][j][r], base);      // base*(1+w)
                }
            } else {
                #pragma unroll
                for (int r = 0; r < 4; ++r) v[r] = fmaxf(acc[i][j][r], 0.f);
            }
            uint2 H, L;
            pack4(v, H, L);
            *(uint2*)(oh + p * LDCO + cs) = H;
            *(uint2*)(ol + p * LDCO + cs) = L;
        }
    }
}

// ---------------- dense kernel: 32 pts / 256 threads / 4 waves / 24KB LDS ----------------
__global__ __launch_bounds__(256, 6) void pointnet_sa(
    const float* __restrict__ xyz, const float* __restrict__ new_xyz,
    const int* __restrict__ idx,
    const short* __restrict__ ws, const short* __restrict__ ftH, const short* __restrict__ ftL,
    const float* __restrict__ bg, const float* __restrict__ b1,
    const float* __restrict__ b2, const float* __restrict__ b3,
    float* __restrict__ out_pooled)  // (B, 256, P)
{
    __shared__ alignas(16) short smem[12288];      // 24 KB
    short* NFh = smem;                              // [32][128]
    short* NFl = smem + 4096;
    short* X0h = smem + 8192;                       // [32][64]
    short* X0l = smem + 10240;
    // X1  = NF cols 0-63 (stride 128); X2P = X0 region (stride 64); X2Q = NF cols 64-127

    const int tid = threadIdx.x, lane = tid & 63, wave = tid >> 6;  // wave 0..3
    const int q = lane >> 4, n16 = lane & 15;
    const int pt0 = blockIdx.x * 32;               // one s-group per block
    const int b = pt0 >> 16;
    const size_t fbase = (size_t)b * kN;

    // ---- gather: 8 threads/point, 4x uint4 load + swizzled b128 stores ----
    {
        const int gp = tid >> 3, gc = tid & 7;     // gp in [0,32)
        const int pt = pt0 + gp;
        const int n = idx[pt];
        const short* rH = ftH + (fbase + n) * 128;
        const short* rL = ftL + (fbase + n) * 128;
        uint4 hc0 = *(const uint4*)(rH + gc * 8);
        uint4 hc1 = *(const uint4*)(rH + gc * 8 + 64);
        uint4 lc0 = *(const uint4*)(rL + gc * 8);
        uint4 lc1 = *(const uint4*)(rL + gc * 8 + 64);
        if (gc == 0) {                              // merge xyz-diff into cols 0..2
            const float* xp = xyz + (fbase + n) * 3;
            const int pp = (pt >> 5) & (kP - 1);
            const float* np = new_xyz + ((size_t)b * kP + pp) * 3;
            union { uint4 u; short s[8]; } H, L;
            H.u = hc0; L.u = lc0;
            #pragma unroll
            for (int c = 0; c < 3; ++c) {
                const float v = xp[c] - np[c];
                const unsigned short hh = f2bf(v);
                H.s[c] = (short)hh;
                L.s[c] = (short)f2bf(v - bf2f(hh));
            }
            hc0 = H.u; lc0 = L.u;
        }
        const int sw = (gc ^ (gp & 7)) * 8;         // chunk-level XOR swizzle
        *(uint4*)(NFh + gp * 128 + sw)      = hc0;
        *(uint4*)(NFh + gp * 128 + sw + 64) = hc1;
        *(uint4*)(NFl + gp * 128 + sw)      = lc0;
        *(uint4*)(NFl + gp * 128 + sw + 64) = lc1;
    }
    __syncthreads();

    // ---- stage g: each wave = 1 o-tile x 2 p-tiles ----
    {
        f32x4 a[1][2];
        gemm_core<1, 2, 4, 128, 128, true>(NFh, NFl, ws + WG_HI, ws + WG_LO, bg, 0,
                                           wave, 0, lane, a);
        store_act<1, 2, true, 64>(a, X0h, X0l, NFh, NFl, wave, 0, lane);
    }
    __syncthreads();                               // B1: NF dead

    // ---- stage 1: read X0 -> X1 (NF cols 0-63, stride 128) ----
    {
        f32x4 a[1][2];
        gemm_core<1, 2, 2, 64, 64, true>(X0h, X0l, ws + W1_HI, ws + W1_LO, b1, 0,
                                         wave, 0, lane, a);
        store_act<1, 2, false, 128>(a, NFh, NFl, nullptr, nullptr, wave, 0, lane);
    }
    __syncthreads();                               // B2: X0 dead

    // ---- stage 2: read X1 -> X2 split (X2P = X0 region, X2Q = NF cols 64-127) ----
    {
        f32x4 a[2][2];
        gemm_core<2, 2, 2, 128, 64, true>(NFh, NFl, ws + W2_HI, ws + W2_LO, b2, 0,
                                          2 * wave, 0, lane, a);
        if (wave < 2)
            store_act<2, 2, false, 64>(a, X0h, X0l, nullptr, nullptr, 2 * wave, 0, lane);
        else
            store_act<2, 2, false, 128>(a, NFh + 64, NFl + 64, nullptr, nullptr,
                                        2 * wave - 4, 0, lane);
    }
    __syncthreads();                               // B3: X2 visible

    // ---- stage 3: each wave = 4 o-tiles x 2 p-tiles; K split X2P | X2Q; pool ----
    {
        f32x4 a[4][2];
        gemm_core<4, 2, 2, 64, 128, true >(X0h, X0l, ws + W3_HI, ws + W3_LO, b3, 0,
                                           4 * wave, 0, lane, a);
        gemm_core<4, 2, 2, 128, 128, false>(NFh + 64, NFl + 64, ws + W3_HI, ws + W3_LO,
                                            nullptr, 64, 4 * wave, 0, lane, a);
        const int g = blockIdx.x;                  // flat b*P + p (one point/block)
        float* outp = out_pooled + ((size_t)(g >> 11) * 256) * kP + (g & (kP - 1));
        #pragma unroll
        for (int i = 0; i < 4; ++i) {
            #pragma unroll
            for (int r = 0; r < 4; ++r) {
                float v = fmaxf(a[i][0][r], a[i][1][r]);   // both p-tiles = full s-group
                v = fmaxf(v, __shfl_xor(v, 1, 16));
                v = fmaxf(v, __shfl_xor(v, 2, 16));
                v = fmaxf(v, __shfl_xor(v, 4, 16));
                v = fmaxf(v, __shfl_xor(v, 8, 16));
                v = fmaxf(v, 0.f);
                if (n16 == 0) {
                    const int o = (4 * wave + i) * 16 + 4 * q + r;
                    outp[(size_t)o * kP] = v;
                }
            }
        }
    }
}

// ---------------- scalar fallback (features in original layout; v10-compact) ----------------
__global__ __launch_bounds__(512, 2) void pointnet_sa_scalar(
    const float* __restrict__ xyz, const float* __restrict__ features,
    const float* __restrict__ new_xyz, const int* __restrict__ idx,
    const short* __restrict__ ws,
    const float* __restrict__ bg, const float* __restrict__ b1,
    const float* __restrict__ b2, const float* __restrict__ b3,
    float* __restrict__ out_pooled)
{
    __shared__ alignas(16) short smem[24576];
    short* NFh = smem;
    short* NFl = smem + 8192;
    short* X0h = smem + 16384;
    short* X0l = smem + 20480;

    const int tid = threadIdx.x, lane = tid & 63, wave = tid >> 6;
    const int q = lane >> 4, n16 = lane & 15;
    const int pt0 = blockIdx.x * 64;
    const int b = pt0 >> 16;

    {
        const int p = tid & 63;
        const int cg = tid >> 6;
        const int pt = pt0 + p;
        const int n = idx[pt];
        const int pp = (pt >> 5) & (kP - 1);
        const float* fbp = features + (size_t)b * kC * kN + n;
        const float* xp = xyz + ((size_t)b * kN + n) * 3;
        const float* np = new_xyz + ((size_t)b * kP + pp) * 3;
        for (int c = cg; c < 128; c += 8) {
            float v;
            if (c < 3)        v = xp[c] - np[c];
            else if (c < 106) v = fbp[(size_t)(c - 3) * kN];
            else              v = 0.f;
            const unsigned short h = f2bf(v);
            const int cs = c ^ ((p & 7) << 3);
            NFh[p * 128 + cs] = (short)h;
            NFl[p * 128 + cs] = (short)f2bf(v - bf2f(h));
        }
    }
    __syncthreads();
    {
        f32x4 a[1][2];
        gemm_core<1, 2, 4, 128, 128, true>(NFh, NFl, ws + WG_HI, ws + WG_LO, bg, 0,
                                           wave & 3, 2 * (wave >> 2), lane, a);
        store_act<1, 2, true, 64>(a, X0h, X0l, NFh, NFl, wave & 3, 2 * (wave >> 2), lane);
    }
    __syncthreads();
    {
        f32x4 a[1][2];
        gemm_core<1, 2, 2, 64, 64, true>(X0h, X0l, ws + W1_HI, ws + W1_LO, b1, 0,
                                         wave & 3, 2 * (wave >> 2), lane, a);
        store_act<1, 2, false, 128>(a, NFh, NFl, nullptr, nullptr,
                                    wave & 3, 2 * (wave >> 2), lane);
    }
    __syncthreads();
    {
        f32x4 a[2][2];
        gemm_core<2, 2, 2, 128, 64, true>(NFh, NFl, ws + W2_HI, ws + W2_LO, b2, 0,
                                          2 * (wave & 3), 2 * (wave >> 2), lane, a);
        if ((wave & 3) < 2)
            store_act<2, 2, false, 64>(a, X0h, X0l, nullptr, nullptr,
                                       2 * (wave & 3), 2 * (wave >> 2), lane);
        else
            store_act<2, 2, false, 128>(a, NFh + 64, NFl + 64, nullptr, nullptr,
                                        (2 * (wave & 3)) & 3, 2 * (wave >> 2), lane);
    }
    __syncthreads();
    {
        f32x4 a[2][4];
        gemm_core<2, 4, 2, 64, 128, true >(X0h, X0l, ws + W3_HI, ws + W3_LO, b3, 0,
                                           2 * wave, 0, lane, a);
        gemm_core<2, 4, 2, 128, 128, false>(NFh + 64, NFl + 64, ws + W3_HI, ws + W3_LO,
                                            nullptr, 64, 2 * wave, 0, lane, a);
        #pragma unroll
        for (int i = 0; i < 2; ++i)
            #pragma unroll
            for (int sg = 0; sg < 2; ++sg)
                #pragma unroll
                for (int r = 0; r < 4; ++r) {
                    float v = fmaxf(a[i][2 * sg][r], a[i][2 * sg + 1][r]);
                    v = fmaxf(v, __shfl_xor(v, 1, 16));
                    v = fmaxf(v, __shfl_xor(v, 2, 16));
                    v = fmaxf(v, __shfl_xor(v, 4, 16));
                    v = fmaxf(v, __shfl_xor(v, 8, 16));
                    v = fmaxf(v, 0.f);
                    if (n16 == 0) {
                        const int o = (2 * wave + i) * 16 + 4 * q + r;
                        const int g = (pt0 >> 5) + sg;
                        out_pooled[((size_t)(g >> 11) * 256 + o) * kP + (g & (kP - 1))] = v;
                    }
                }
    }
}
}  // namespace

extern "C" void kernel_launch(void* const* d_in, const int* in_sizes, int n_in,
                              void* d_out, int out_size, void* d_ws, size_t ws_size,
                              hipStream_t stream) {
    const float* xyz      = (const float*)d_in[0];
    const float* features = (const float*)d_in[1];
    const float* new_xyz  = (const float*)d_in[2];
    const int*   idx      = (const int*)d_in[3];
    const float* Wg = (const float*)d_in[4];
    const float* bg = (const float*)d_in[5];
    const float* W1 = (const float*)d_in[6];
    const float* b1 = (const float*)d_in[7];
    const float* W2 = (const float*)d_in[8];
    const float* b2 = (const float*)d_in[9];
    const float* W3 = (const float*)d_in[10];
    const float* b3 = (const float*)d_in[11];
    float* out = (float*)d_out;
    short* ws  = (short*)d_ws;
    short* ftH = (short*)((char*)d_ws + FT_OFF);
    short* ftL = ftH + FT_SHORTS;

    const int nxyz = kB * kP * 3;
    copy_newxyz<<<(nxyz + 255) / 256, 256, 0, stream>>>(new_xyz, out, nxyz);
    prep_weights<<<(53248 + 255) / 256, 256, 0, stream>>>(Wg, W1, W2, W3, ws);

    float* pooled = out + nxyz;
    if (ws_size >= WS_NEED) {
        prep_feat<<<kB * (kN / 64), 512, 0, stream>>>(features, ftH, ftL);
        pointnet_sa<<<(kB * kP * kS) / 32, 256, 0, stream>>>(
            xyz, new_xyz, idx, ws, ftH, ftL, bg, b1, b2, b3, pooled);
    } else {
        pointnet_sa_scalar<<<(kB * kP * kS) / 64, 512, 0, stream>>>(
            xyz, features, new_xyz, idx, ws, bg, b1, b2, b3, pooled);
    }
}

// Round 18
// 183.151 us; speedup vs baseline: 1.3430x; 1.2440x over previous
//
#include <hip/hip_runtime.h>
#include <stdint.h>

// PointNet SA via MFMA, v13 = v10 structure (64 pts / 512 thr / 48KB LDS, best
// measured 184.8us) + WEIGHT REGISTER PREFETCH: gemm_core loads ALL its A-frag
// weights into SSA registers BEFORE the MFMA chain (one latency exposure instead
// of KT serial ~200cy L2 hits inside the dependent chain — v10's VGPR=48 shows
// the compiler hoisted nothing). __launch_bounds__(512,2) for the VGPR headroom
// (measured occupancy was 2 blocks/CU anyway). + cvt_pk packing (absmax-neutral).

namespace {
constexpr int kB = 4, kN = 16384, kC = 103, kP = 2048, kS = 32;

using short8 = __attribute__((ext_vector_type(8))) short;
using short4 = __attribute__((ext_vector_type(4))) short;
using f32x4  = __attribute__((ext_vector_type(4))) float;

constexpr int WG_HI = 0,     WG_LO = 8192;     // 64 x 128
constexpr int W1_HI = 16384, W1_LO = 20480;    // 64 x 64
constexpr int W2_HI = 24576, W2_LO = 32768;    // 128 x 64
constexpr int W3_HI = 40960, W3_LO = 73728;    // 256 x 128
constexpr size_t FT_OFF    = 262144;
constexpr size_t FT_SHORTS = (size_t)kB * kN * 128;
constexpr size_t WS_NEED   = FT_OFF + 2 * FT_SHORTS * 2;

__device__ __forceinline__ unsigned short f2bf(float x) {
    unsigned u = __float_as_uint(x);
    u += 0x7fffu + ((u >> 16) & 1u);           // RNE
    return (unsigned short)(u >> 16);
}
__device__ __forceinline__ float bf2f(unsigned short h) {
    return __uint_as_float((unsigned)h << 16);
}
__device__ __forceinline__ unsigned cvtpk(float a, float b) {
    unsigned r;
    asm("v_cvt_pk_bf16_f32 %0, %1, %2" : "=v"(r) : "v"(a), "v"(b));
    return r;
}
// pack 4 f32 -> hi-plane uint2 + lo-plane uint2 (hi/lo bf16 split, RNE)
__device__ __forceinline__ void pack4(const float v[4], uint2& H, uint2& L) {
    H.x = cvtpk(v[0], v[1]);
    H.y = cvtpk(v[2], v[3]);
    const float r0 = v[0] - __uint_as_float(H.x << 16);
    const float r1 = v[1] - __uint_as_float(H.x & 0xffff0000u);
    const float r2 = v[2] - __uint_as_float(H.y << 16);
    const float r3 = v[3] - __uint_as_float(H.y & 0xffff0000u);
    L.x = cvtpk(r0, r1);
    L.y = cvtpk(r2, r3);
}

__global__ void copy_newxyz(const float* __restrict__ src, float* __restrict__ dst, int n) {
    int i = blockIdx.x * blockDim.x + threadIdx.x;
    if (i < n) dst[i] = src[i];
}

__global__ void prep_weights(const float* __restrict__ Wg, const float* __restrict__ W1,
                             const float* __restrict__ W2, const float* __restrict__ W3,
                             short* __restrict__ ws) {
    int i = blockIdx.x * blockDim.x + threadIdx.x;
    if (i >= 53248) return;
    float w; int hi, lo, j;
    if (i < 8192)       { j = i;         int o = j >> 7, c = j & 127; w = (c < 106) ? Wg[o * 106 + c] : 0.f; hi = WG_HI; lo = WG_LO; }
    else if (i < 12288) { j = i - 8192;  int o = j >> 6, c = j & 63;  w = W1[o * 64 + c];  hi = W1_HI; lo = W1_LO; }
    else if (i < 20480) { j = i - 12288; int o = j >> 6, c = j & 63;  w = W2[o * 64 + c];  hi = W2_HI; lo = W2_LO; }
    else                { j = i - 20480; int o = j >> 7, c = j & 127; w = W3[o * 128 + c]; hi = W3_HI; lo = W3_LO; }
    unsigned short h = f2bf(w);
    ws[hi + j] = (short)h;
    ws[lo + j] = (short)f2bf(w - bf2f(h));
}

__global__ __launch_bounds__(512) void prep_feat(const float* __restrict__ f,
                                                 short* __restrict__ ftH, short* __restrict__ ftL) {
    __shared__ float tile[kC][65];
    const int bb = blockIdx.x >> 8;
    const int n0 = (blockIdx.x & 255) * 64;
    const int tid = threadIdx.x;
    for (int c = tid >> 6; c < kC; c += 8)
        tile[c][tid & 63] = f[((size_t)bb * kC + c) * kN + n0 + (tid & 63)];
    __syncthreads();
    const int np = tid >> 3, gc = tid & 7;
    short* rH = ftH + ((size_t)bb * kN + n0 + np) * 128;
    short* rL = ftL + ((size_t)bb * kN + n0 + np) * 128;
    #pragma unroll
    for (int kk = 0; kk < 2; ++kk) {
        const int chunk = gc + 8 * kk;
        union { uint4 u; short s[8]; } H, L;
        #pragma unroll
        for (int e = 0; e < 8; ++e) {
            const int col = chunk * 8 + e;
            float v = (col >= 3 && col < 106) ? tile[col - 3][np] : 0.f;
            unsigned short hh = f2bf(v);
            H.s[e] = (short)hh;
            L.s[e] = (short)f2bf(v - bf2f(hh));
        }
        *(uint4*)(rH + chunk * 8) = H.u;
        *(uint4*)(rL + chunk * 8) = L.u;
    }
}

// A: m=lane&15 (W row), k=8*(lane>>4)+j; B: n=lane&15 (point), same k; D: n=lane&15, m=4*(lane>>4)+r
// WEIGHT PREFETCH: all NOT*KT*2 weight frags load into SSA regs before the chain.
template<int NOT, int NPT, int KT, int LDC, int LDW, bool INIT>
__device__ __forceinline__ void gemm_core(
    const short* __restrict__ xh, const short* __restrict__ xl,
    const short* __restrict__ wh, const short* __restrict__ wl,
    const float* __restrict__ bias, int kwoff,
    int ot0, int pt0t, int lane, f32x4 (&acc)[NOT][NPT])
{
    const int q = lane >> 4, n16 = lane & 15;
    short8 whr[NOT * KT], wlr[NOT * KT];           // static-indexed, fully unrolled -> regs
    #pragma unroll
    for (int i = 0; i < NOT; ++i)
        #pragma unroll
        for (int kt = 0; kt < KT; ++kt) {
            const size_t we = (size_t)((ot0 + i) * 16 + n16) * LDW + kwoff + kt * 32 + q * 8;
            whr[i * KT + kt] = *(const short8*)(wh + we);
            wlr[i * KT + kt] = *(const short8*)(wl + we);
        }
    if constexpr (INIT) {
        #pragma unroll
        for (int i = 0; i < NOT; ++i) {
            const f32x4 binit = *(const f32x4*)(bias + (ot0 + i) * 16 + 4 * q);
            #pragma unroll
            for (int j = 0; j < NPT; ++j) acc[i][j] = binit;
        }
    }
    #pragma unroll
    for (int kt = 0; kt < KT; ++kt) {
        const int k0 = kt * 32 + q * 8;
        short8 bh[NPT], bl[NPT];
        #pragma unroll
        for (int j = 0; j < NPT; ++j) {
            const int p = (pt0t + j) * 16 + n16;
            const int e = p * LDC + (k0 ^ ((p & 7) << 3));
            bh[j] = *(const short8*)(xh + e);
            bl[j] = *(const short8*)(xl + e);
        }
        #pragma unroll
        for (int i = 0; i < NOT; ++i) {
            const short8 ah = whr[i * KT + kt];
            const short8 al = wlr[i * KT + kt];
            #pragma unroll
            for (int j = 0; j < NPT; ++j) {
                acc[i][j] = __builtin_amdgcn_mfma_f32_16x16x32_bf16(ah, bh[j], acc[i][j], 0, 0, 0);
                acc[i][j] = __builtin_amdgcn_mfma_f32_16x16x32_bf16(ah, bl[j], acc[i][j], 0, 0, 0);
                acc[i][j] = __builtin_amdgcn_mfma_f32_16x16x32_bf16(al, bh[j], acc[i][j], 0, 0, 0);
            }
        }
    }
}

// GATE: v = base*(1+acc) with base from NF planes; else relu. cvt_pk packing.
template<int NOT, int NPT, bool GATE, int LDCO>
__device__ __forceinline__ void store_act(
    f32x4 (&acc)[NOT][NPT], short* __restrict__ oh, short* __restrict__ ol,
    const short* __restrict__ nfh, const short* __restrict__ nfl,
    int ot0, int pt0t, int lane)
{
    const int q = lane >> 4, n16 = lane & 15;
    #pragma unroll
    for (int i = 0; i < NOT; ++i) {
        const int ob = (ot0 + i) * 16 + 4 * q;
        #pragma unroll
        for (int j = 0; j < NPT; ++j) {
            const int p = (pt0t + j) * 16 + n16;
            const int cs = ob ^ ((p & 7) << 3);
            float v[4];
            if (GATE) {
                const short4 h4 = *(const short4*)(nfh + p * 128 + cs);
                const short4 l4 = *(const short4*)(nfl + p * 128 + cs);
                #pragma unroll
                for (int r = 0; r < 4; ++r) {
                    const float base = bf2f((unsigned short)h4[r]) + bf2f((unsigned short)l4[r]);
                    v[r] = fmaf(base, acc[i][j][r], base);      // base*(1+w)
                }
            } else {
                #pragma unroll
                for (int r = 0; r < 4; ++r) v[r] = fmaxf(acc[i][j][r], 0.f);
            }
            uint2 H, L;
            pack4(v, H, L);
            *(uint2*)(oh + p * LDCO + cs) = H;
            *(uint2*)(ol + p * LDCO + cs) = L;
        }
    }
}

// ---------------- dense kernel: v10 structure, 64 pts / 512 thr / 48KB ----------------
template<bool DENSE>
__global__ __launch_bounds__(512, 2) void pointnet_sa(
    const float* __restrict__ xyz, const float* __restrict__ features,
    const float* __restrict__ new_xyz, const int* __restrict__ idx,
    const short* __restrict__ ws, const short* __restrict__ ftH, const short* __restrict__ ftL,
    const float* __restrict__ bg, const float* __restrict__ b1,
    const float* __restrict__ b2, const float* __restrict__ b3,
    float* __restrict__ out_pooled)  // (B, 256, P)
{
    __shared__ alignas(16) short smem[24576];      // 48 KB
    short* NFh = smem;                              // [64][128]
    short* NFl = smem + 8192;
    short* X0h = smem + 16384;                      // [64][64]
    short* X0l = smem + 20480;
    // X1  = NF cols 0-63 (stride 128); X2P = X0 region (stride 64); X2Q = NF cols 64-127

    const int tid = threadIdx.x, lane = tid & 63, wave = tid >> 6;
    const int q = lane >> 4, n16 = lane & 15;
    const int pt0 = blockIdx.x * 64;
    const int b = pt0 >> 16;                        // P*S = 65536 points per batch

    if (DENSE) {
        // ---- dense gather: 8 threads/point, 4x uint4 load + swizzled b128 stores ----
        const int gp = tid >> 3, gc = tid & 7;
        const int pt = pt0 + gp;
        const int n = idx[pt];
        const short* rH = ftH + ((size_t)b * kN + n) * 128;
        const short* rL = ftL + ((size_t)b * kN + n) * 128;
        uint4 hc0 = *(const uint4*)(rH + gc * 8);
        uint4 hc1 = *(const uint4*)(rH + gc * 8 + 64);
        uint4 lc0 = *(const uint4*)(rL + gc * 8);
        uint4 lc1 = *(const uint4*)(rL + gc * 8 + 64);
        if (gc == 0) {                              // merge xyz-diff into cols 0..2
            const float* xp = xyz + ((size_t)b * kN + n) * 3;
            const int pp = (pt >> 5) & (kP - 1);
            const float* np = new_xyz + ((size_t)b * kP + pp) * 3;
            union { uint4 u; short s[8]; } H, L;
            H.u = hc0; L.u = lc0;
            #pragma unroll
            for (int c = 0; c < 3; ++c) {
                const float v = xp[c] - np[c];
                const unsigned short hh = f2bf(v);
                H.s[c] = (short)hh;
                L.s[c] = (short)f2bf(v - bf2f(hh));
            }
            hc0 = H.u; lc0 = L.u;
        }
        const int sw = (gc ^ (gp & 7)) * 8;         // chunk-level XOR swizzle
        *(uint4*)(NFh + gp * 128 + sw)      = hc0;
        *(uint4*)(NFh + gp * 128 + sw + 64) = hc1;
        *(uint4*)(NFl + gp * 128 + sw)      = lc0;
        *(uint4*)(NFl + gp * 128 + sw + 64) = lc1;
    } else {
        // ---- fallback: scalar gather from original features layout ----
        const int p = tid & 63;
        const int cg = tid >> 6;
        const int pt = pt0 + p;
        const int n = idx[pt];
        const int pp = (pt >> 5) & (kP - 1);
        const float* fbp = features + (size_t)b * kC * kN + n;
        const float* xp = xyz + ((size_t)b * kN + n) * 3;
        const float* np = new_xyz + ((size_t)b * kP + pp) * 3;
        for (int c = cg; c < 128; c += 8) {
            float v;
            if (c < 3)        v = xp[c] - np[c];
            else if (c < 106) v = fbp[(size_t)(c - 3) * kN];
            else              v = 0.f;
            const unsigned short h = f2bf(v);
            const int cs = c ^ ((p & 7) << 3);
            NFh[p * 128 + cs] = (short)h;
            NFl[p * 128 + cs] = (short)f2bf(v - bf2f(h));
        }
    }
    __syncthreads();

    // ---- stage g: w = Wg*nf + bg ; x0 = nf[:64]*(1+w) -> X0 region ----
    {
        f32x4 a[1][2];
        gemm_core<1, 2, 4, 128, 128, true>(NFh, NFl, ws + WG_HI, ws + WG_LO, bg, 0,
                                           wave & 3, 2 * (wave >> 2), lane, a);
        store_act<1, 2, true, 64>(a, X0h, X0l, NFh, NFl, wave & 3, 2 * (wave >> 2), lane);
    }
    __syncthreads();                               // B1: NF dead

    // ---- stage 1: read X0, write X1 into NF cols 0-63 (stride 128) ----
    {
        f32x4 a[1][2];
        gemm_core<1, 2, 2, 64, 64, true>(X0h, X0l, ws + W1_HI, ws + W1_LO, b1, 0,
                                         wave & 3, 2 * (wave >> 2), lane, a);
        store_act<1, 2, false, 128>(a, NFh, NFl, nullptr, nullptr,
                                    wave & 3, 2 * (wave >> 2), lane);
    }
    __syncthreads();                               // B2: X0 dead

    // ---- stage 2: read X1 (NF stride 128, cols<64), write X2 split P/Q ----
    {
        f32x4 a[2][2];
        gemm_core<2, 2, 2, 128, 64, true>(NFh, NFl, ws + W2_HI, ws + W2_LO, b2, 0,
                                          2 * (wave & 3), 2 * (wave >> 2), lane, a);
        if ((wave & 3) < 2)                         // o-tiles 0-3 -> X2P (X0 region)
            store_act<2, 2, false, 64>(a, X0h, X0l, nullptr, nullptr,
                                       2 * (wave & 3), 2 * (wave >> 2), lane);
        else                                        // o-tiles 4-7 -> X2Q (NF cols 64-127)
            store_act<2, 2, false, 128>(a, NFh + 64, NFl + 64, nullptr, nullptr,
                                        (2 * (wave & 3)) & 3, 2 * (wave >> 2), lane);
    }
    __syncthreads();                               // B3

    // ---- stage 3: acc over X2P (k 0-63) then X2Q (k 64-127), + max-pool ----
    {
        f32x4 a[2][4];
        gemm_core<2, 4, 2, 64, 128, true >(X0h, X0l, ws + W3_HI, ws + W3_LO, b3, 0,
                                           2 * wave, 0, lane, a);
        gemm_core<2, 4, 2, 128, 128, false>(NFh + 64, NFl + 64, ws + W3_HI, ws + W3_LO,
                                            nullptr, 64, 2 * wave, 0, lane, a);
        #pragma unroll
        for (int i = 0; i < 2; ++i) {
            #pragma unroll
            for (int sg = 0; sg < 2; ++sg) {
                #pragma unroll
                for (int r = 0; r < 4; ++r) {
                    float v = fmaxf(a[i][2 * sg][r], a[i][2 * sg + 1][r]);
                    v = fmaxf(v, __shfl_xor(v, 1, 16));
                    v = fmaxf(v, __shfl_xor(v, 2, 16));
                    v = fmaxf(v, __shfl_xor(v, 4, 16));
                    v = fmaxf(v, __shfl_xor(v, 8, 16));
                    v = fmaxf(v, 0.f);
                    if (n16 == 0) {
                        const int o = (2 * wave + i) * 16 + 4 * q + r;
                        const int g = (pt0 >> 5) + sg;                 // flat b*P + p
                        out_pooled[((size_t)(g >> 11) * 256 + o) * kP + (g & (kP - 1))] = v;
                    }
                }
            }
        }
    }
}
}  // namespace

extern "C" void kernel_launch(void* const* d_in, const int* in_sizes, int n_in,
                              void* d_out, int out_size, void* d_ws, size_t ws_size,
                              hipStream_t stream) {
    const float* xyz      = (const float*)d_in[0];
    const float* features = (const float*)d_in[1];
    const float* new_xyz  = (const float*)d_in[2];
    const int*   idx      = (const int*)d_in[3];
    const float* Wg = (const float*)d_in[4];
    const float* bg = (const float*)d_in[5];
    const float* W1 = (const float*)d_in[6];
    const float* b1 = (const float*)d_in[7];
    const float* W2 = (const float*)d_in[8];
    const float* b2 = (const float*)d_in[9];
    const float* W3 = (const float*)d_in[10];
    const float* b3 = (const float*)d_in[11];
    float* out = (float*)d_out;
    short* ws  = (short*)d_ws;
    short* ftH = (short*)((char*)d_ws + FT_OFF);
    short* ftL = ftH + FT_SHORTS;

    const int nxyz = kB * kP * 3;
    copy_newxyz<<<(nxyz + 255) / 256, 256, 0, stream>>>(new_xyz, out, nxyz);
    prep_weights<<<(53248 + 255) / 256, 256, 0, stream>>>(Wg, W1, W2, W3, ws);

    float* pooled = out + nxyz;
    if (ws_size >= WS_NEED) {
        prep_feat<<<kB * (kN / 64), 512, 0, stream>>>(features, ftH, ftL);
        pointnet_sa<true><<<(kB * kP * kS) / 64, 512, 0, stream>>>(
            xyz, features, new_xyz, idx, ws, ftH, ftL, bg, b1, b2, b3, pooled);
    } else {
        pointnet_sa<false><<<(kB * kP * kS) / 64, 512, 0, stream>>>(
            xyz, features, new_xyz, idx, ws, nullptr, nullptr, bg, b1, b2, b3, pooled);
    }
}